// Round 11
// baseline (133.065 us; speedup 1.0000x reference)
//
#include <hip/hip_runtime.h>
#include <hip/hip_bf16.h>

typedef unsigned short u16;
typedef unsigned int   u32;

using bf16x8 = __attribute__((ext_vector_type(8))) short;  // 8 bf16 in 4 VGPRs
using f32x4  = __attribute__((ext_vector_type(4))) float;  // MFMA accumulator

#define NB 32
#define NP 1024
#define ND 256

__device__ __forceinline__ u16 f2bf(float x){
  u32 u = __float_as_uint(x);
  u += 0x7FFFu + ((u >> 16) & 1u);   // round-to-nearest-even
  return (u16)(u >> 16);
}

__device__ __forceinline__ float bf2f(u16 x){
  return __uint_as_float((u32)x << 16);
}

__device__ __forceinline__ void glds16(const void* g, void* l){
  __builtin_amdgcn_global_load_lds((const __attribute__((address_space(1))) void*)g,
                                   (__attribute__((address_space(3))) void*)l, 16, 0, 0);
}

// ---------------- prep 1: Pbf = bf16(P), sbv[row] = P[row,:] . wb ----------------
__global__ void prep_rows(const float* __restrict__ P, const float* __restrict__ wi,
                          u16* __restrict__ Pbf, float* __restrict__ sbv){
  const int row  = blockIdx.x * 4 + (threadIdx.x >> 6);   // one wave per row
  const int lane = threadIdx.x & 63;
  const float4 p  = *(const float4*)(P  + (size_t)row * ND + lane * 4);
  const float4 wb = *(const float4*)(wi + ND + lane * 4);  // wb = wi[256:512]
  ushort4 pb;
  pb.x = f2bf(p.x); pb.y = f2bf(p.y); pb.z = f2bf(p.z); pb.w = f2bf(p.w);
  *(ushort4*)(Pbf + (size_t)row * ND + lane * 4) = pb;
  float s = p.x*wb.x + p.y*wb.y + p.z*wb.z + p.w*wb.w;
  #pragma unroll
  for (int m = 1; m < 64; m <<= 1) s += __shfl_xor(s, m, 64);
  if (lane == 0) sbv[row] = s;
}

// ------- prep 2: pack W fragment-major: Wp[((t*16+c)*64+lane)*8 + e] -------------
__global__ void prep_w(const float* __restrict__ w1, const float* __restrict__ w2,
                       const float* __restrict__ w3, u16* __restrict__ Wp){
  const int t = blockIdx.x;                       // 0..47
  const float* w = (t < 16) ? w1 : ((t < 32) ? w2 : w3);
  const int tid = threadIdx.x;
  #pragma unroll
  for (int j = 0; j < 4; ++j){
    int item = tid + 256 * j;                     // c*64 + lane
    int c = item >> 6, lane = item & 63;
    int ncol = ((t & 15) << 4) + (lane & 15);
    int k0 = 32 * c + 8 * (lane >> 4);
    u16 tmp[8];
    #pragma unroll
    for (int e = 0; e < 8; ++e) tmp[e] = f2bf(w[(size_t)(k0 + e) * 256 + ncol]);
    *(uint4*)(Wp + ((size_t)(t * 16 + c) * 64 + lane) * 8) = *(uint4*)tmp;
  }
}

// ---------------- prep 3: PbfT[b][d][j] = Pbf[b][j][d] (64x64 LDS tiles) ---------
__global__ void transpose_p(const u16* __restrict__ Pbf, u16* __restrict__ PbfT){
  const int b = blockIdx.z, jt = blockIdx.x, dt = blockIdx.y;
  __shared__ u16 T[64][72];
  const int tid = threadIdx.x;
  #pragma unroll
  for (int it = 0; it < 2; ++it){
    int cc = tid + 256 * it;               // 0..511: 64 j-rows x 8 chunks
    int j = cc >> 3, c8 = cc & 7;
    uint4 v = *(const uint4*)(Pbf + ((size_t)b * NP + jt * 64 + j) * ND + dt * 64 + c8 * 8);
    *(uint4*)&T[j][c8 * 8] = v;
  }
  __syncthreads();
  #pragma unroll
  for (int it = 0; it < 2; ++it){
    int cc = tid + 256 * it;               // 64 d-rows x 8 chunks
    int d = cc >> 3, c8 = cc & 7;
    u16 tmp[8];
    #pragma unroll
    for (int k = 0; k < 8; ++k) tmp[k] = T[c8 * 8 + k][d];
    *(uint4*)(PbfT + ((size_t)b * ND + dt * 64 + d) * NP + jt * 64 + c8 * 8) = *(uint4*)tmp;
  }
}

// ---------------- attention: 2-wave blocks, QBLK=32, KBLK=32, 4 blocks/CU --------
// r10 accounting: LDS issue was only ~50% busy with 2 big barrier-synced blocks/CU
// (phases align, LDS idles during softmax/barriers). Same 8 waves/CU here but in
// 4 INDEPENDENT barrier domains -> finer interleave. Layouts (validated rule:
// b128 conflict-free iff quad=(addr/16)%8 bijects (lo&7) at fixed hi):
//   K: phys = j*512 + 16*(ck ^ (j&7))  -> read quad = (4(c&1)+hi)^(lo&7)  OK
//   V: phys = d*64  + 16*(kc ^ (d&3))  -> read quad = 4(lo&1)+(hi^(lo&3)) =
//      4 quads x 2 lanes = 2-way, free per m136.
// glds sources = whole-row permutations (coalesced). Split-barrier pipeline as
// r10. T5 setprio around MFMA clusters (4 desynced groups give it arbitrage).
__launch_bounds__(128, 2)
__global__ void attn_kernel(const float* __restrict__ P, const float* __restrict__ wi,
                            const u16* __restrict__ Pbf, const u16* __restrict__ PbfT,
                            const float* __restrict__ sbv, u16* __restrict__ attnb){
  const int p    = blockIdx.x;
  const int bid  = ((p & 7) << 7) | (p >> 3);     // 128 consecutive bids per XCD
  const int b    = bid >> 5;
  const int q0   = (bid & 31) << 5;
  const int tid  = threadIdx.x;
  const int wave = tid >> 6, lane = tid & 63, lo = lane & 15, hi = lane >> 4;

  __shared__ __align__(16) u16 KtA[32 * 256];     // 16 KB
  __shared__ __align__(16) u16 VtA[256 * 32];     // 16 KB
  __shared__ __align__(16) u16 Sp[2][16][40];     // 2.5 KB
  char* KtB = (char*)KtA;
  char* VtB = (char*)VtA;

  // ---- Q fragments (A-operand): q = P * wc, bf16, in regs ----
  bf16x8 qf[8];
  {
    const int qrow = q0 + wave * 16 + lo;
    const float* prow = P  + ((size_t)b * NP + qrow) * ND;
    const float* wcp  = wi + 512;
    #pragma unroll
    for (int c = 0; c < 8; ++c){
      const int d0 = 32 * c + 8 * hi;
      float4 a  = *(const float4*)(prow + d0);
      float4 a2 = *(const float4*)(prow + d0 + 4);
      float4 wa  = *(const float4*)(wcp + d0);
      float4 wa2 = *(const float4*)(wcp + d0 + 4);
      bf16x8 q;
      q[0]=(short)f2bf(a.x*wa.x);  q[1]=(short)f2bf(a.y*wa.y);
      q[2]=(short)f2bf(a.z*wa.z);  q[3]=(short)f2bf(a.w*wa.w);
      q[4]=(short)f2bf(a2.x*wa2.x); q[5]=(short)f2bf(a2.y*wa2.y);
      q[6]=(short)f2bf(a2.z*wa2.z); q[7]=(short)f2bf(a2.w*wa2.w);
      qf[c] = q;
    }
  }

  f32x4 of[16];
  #pragma unroll
  for (int t = 0; t < 16; ++t) of[t] = (f32x4){0.f,0.f,0.f,0.f};
  float mx[4] = {-1e30f,-1e30f,-1e30f,-1e30f};
  float ls[4] = {0.f,0.f,0.f,0.f};

  const u16* kslab = Pbf  + (size_t)b * NP * ND;   // row-major [j][d]
  const u16* vslab = PbfT + (size_t)b * ND * NP;   // d-major  [d][j]

  auto stageK = [&](int kt){
    const int kbase = kt * 32;
    #pragma unroll
    for (int it = 0; it < 8; ++it){
      int off = it * 2048 + tid * 16;             // linear LDS dest byte
      int j   = off >> 9;                          // key row 0..31
      int ck  = ((off >> 4) & 31) ^ (j & 7);
      glds16((const char*)(kslab + (size_t)(kbase + j) * ND + ck * 8), KtB + off);
    }
  };
  auto stageV = [&](int kt){
    const int kbase = kt * 32;
    #pragma unroll
    for (int it = 0; it < 8; ++it){
      int off = it * 2048 + tid * 16;
      int d   = off >> 6;                          // feature row 0..255
      int kc  = ((off >> 4) & 3) ^ (d & 3);
      glds16((const char*)(vslab + (size_t)d * NP + kbase + kc * 8), VtB + off);
    }
  };

  float sbc[2], sbn[2];
  stageK(0);
  stageV(0);
  #pragma unroll
  for (int nt = 0; nt < 2; ++nt) sbc[nt] = sbv[(size_t)b * NP + nt * 16 + lo];
  __syncthreads();                                 // drain: K0,V0 valid

  for (int kt = 0; kt < 32; ++kt){
    // ---- S = Q K^T (reads Kt; V(kt) glds drained by this iter's entry sync) ----
    f32x4 s[2];
    __builtin_amdgcn_s_setprio(1);
    #pragma unroll
    for (int nt = 0; nt < 2; ++nt){
      f32x4 acc = (f32x4){0.f,0.f,0.f,0.f};
      #pragma unroll
      for (int c = 0; c < 8; ++c){
        int j  = nt * 16 + lo;
        int ad = j * 512 + (((4 * c + hi) ^ (j & 7)) << 4);
        bf16x8 kf = *(const bf16x8*)(KtB + ad);
        acc = __builtin_amdgcn_mfma_f32_16x16x32_bf16(qf[c], kf, acc, 0, 0, 0);
      }
      s[nt] = acc;
    }
    __builtin_amdgcn_s_setprio(0);
    #pragma unroll
    for (int nt = 0; nt < 2; ++nt){
      float sv = sbc[nt];
      #pragma unroll
      for (int r = 0; r < 4; ++r) s[nt][r] += sv;
    }

    __syncthreads();                  // barrier1: both waves done reading Kt
    if (kt < 31) stageK(kt + 1);      // in flight across softmax+PV; drained at barrier2

    // ---- deferred online softmax ----
    float md = -1e30f;
    #pragma unroll
    for (int nt = 0; nt < 2; ++nt)
      #pragma unroll
      for (int r = 0; r < 4; ++r) md = fmaxf(md, s[nt][r] - mx[r]);
    if (!__all(md <= 8.f)){
      // slow path: proper row maxima + rescale (tile 0, rare after)
      float scale[4];
      #pragma unroll
      for (int r = 0; r < 4; ++r){
        float v = fmaxf(s[0][r], s[1][r]);
        v = fmaxf(v, __shfl_xor(v, 1, 64));
        v = fmaxf(v, __shfl_xor(v, 2, 64));
        v = fmaxf(v, __shfl_xor(v, 4, 64));
        v = fmaxf(v, __shfl_xor(v, 8, 64));
        float mnew = fmaxf(mx[r], v);
        scale[r] = __expf(mx[r] - mnew);
        mx[r] = mnew;
        ls[r] *= scale[r];
      }
      #pragma unroll
      for (int t = 0; t < 16; ++t)
        #pragma unroll
        for (int r = 0; r < 4; ++r) of[t][r] *= scale[r];
    }
    // common path: exp, per-lane partial sums, repack (p bounded by e^8)
    #pragma unroll
    for (int nt = 0; nt < 2; ++nt)
      #pragma unroll
      for (int r = 0; r < 4; ++r){
        float pv = __expf(s[nt][r] - mx[r]);
        ls[r] += pv;
        Sp[wave][4 * hi + r][16 * nt + lo] = f2bf(pv);
      }

    // ---- O += P V (reads Vt; Sp is within-wave, no barrier needed) ----
    {
      bf16x8 pa = *(const bf16x8*)&Sp[wave][lo][8 * hi];
      __builtin_amdgcn_s_setprio(1);
      #pragma unroll
      for (int t = 0; t < 16; ++t){
        int d  = 16 * t + lo;
        int ad = d * 64 + ((hi ^ (d & 3)) << 4);
        bf16x8 vb = *(const bf16x8*)(VtB + ad);
        of[t] = __builtin_amdgcn_mfma_f32_16x16x32_bf16(pa, vb, of[t], 0, 0, 0);
      }
      __builtin_amdgcn_s_setprio(0);
    }

    __syncthreads();                  // barrier2: Vt reads done; drains K(t+1) glds
    if (kt < 31){
      stageV(kt + 1);                 // in flight across next QK^T; drained at barrier1
      #pragma unroll
      for (int nt = 0; nt < 2; ++nt)
        sbn[nt] = sbv[(size_t)b * NP + (kt + 1) * 32 + nt * 16 + lo];
      sbc[0] = sbn[0]; sbc[1] = sbn[1];
    }
  }

  // ---- epilogue: one cross-lane ls reduce, O /= l, store bf16 ----
  #pragma unroll
  for (int r = 0; r < 4; ++r){
    ls[r] += __shfl_xor(ls[r], 1, 64);
    ls[r] += __shfl_xor(ls[r], 2, 64);
    ls[r] += __shfl_xor(ls[r], 4, 64);
    ls[r] += __shfl_xor(ls[r], 8, 64);
  }
  const int qrow = q0 + wave * 16;
  #pragma unroll
  for (int t = 0; t < 16; ++t){
    #pragma unroll
    for (int r = 0; r < 4; ++r){
      float o = of[t][r] / ls[r];
      attnb[((size_t)b * NP + qrow + 4 * hi + r) * ND + 16 * t + lo] = f2bf(o);
    }
  }
}

// ---------------- MLP: proper GEMM, M-tile 128, fused gate epilogue --------------
// NOTE: acc[3][8] = 96 VGPRs of accumulator. __launch_bounds__ min-waves MUST stay
// at 2 (VGPR budget 256): round-5's (256,4) capped the allocator at 64 VGPR and
// spilled all accumulators to scratch (WRITE_SIZE 33 -> 325 MB, 18 -> 136 us).
__launch_bounds__(256, 2)
__global__ void mlp_kernel(const u16* __restrict__ Pbf, const u16* __restrict__ attnb,
                           const u16* __restrict__ Wp,
                           const float* __restrict__ b1, const float* __restrict__ b2,
                           const float* __restrict__ b3, float* __restrict__ out){
  const int p    = blockIdx.x;
  const int swz  = ((p & 7) << 7) | (p >> 3);     // XCD-chunked
  const int mt   = swz >> 2, cg = swz & 3;
  const int tid  = threadIdx.x;
  const int wave = tid >> 6, lane = tid & 63, lo = lane & 15, hi = lane >> 4;
  const int tq   = 4 * cg + wave;
  const int m0   = mt * 128;

  __shared__ __align__(16) u16 Ab[2][128 * 64];   // 2 x 16 KB, swizzled

  f32x4 acc[3][8];
  #pragma unroll
  for (int e = 0; e < 3; ++e)
    #pragma unroll
    for (int m = 0; m < 8; ++m) acc[e][m] = (f32x4){0.f,0.f,0.f,0.f};

  auto stage = [&](int s, int buf){
    const u16* xs = (s < 4) ? (Pbf   + (size_t)m0 * ND + s * 64)
                            : (attnb + (size_t)m0 * ND + (s - 4) * 64);
    char* dst = (char*)Ab[buf];
    #pragma unroll
    for (int it = 0; it < 4; ++it){
      int off = it * 4096 + wave * 1024 + lane * 16;   // physical LDS byte
      int row = off >> 7;                               // 128B per row
      int cl  = (off & 127) ^ ((row & 7) << 4);         // logical byte in row
      glds16((const char*)(xs + (size_t)row * ND) + cl, dst + it * 4096 + wave * 1024);
    }
  };

  stage(0, 0);
  __syncthreads();

  for (int s = 0; s < 8; ++s){
    if (s < 7) stage(s + 1, (s + 1) & 1);
    const char* ab = (const char*)Ab[s & 1];
    #pragma unroll
    for (int cc = 0; cc < 2; ++cc){
      const int c = 2 * s + cc;
      bf16x8 wf[3];
      #pragma unroll
      for (int e = 0; e < 3; ++e)
        wf[e] = *(const bf16x8*)(Wp + ((size_t)((tq + 16 * e) * 16 + c) * 64 + lane) * 8);
      #pragma unroll
      for (int m = 0; m < 8; ++m){
        int row = 16 * m + lo;
        bf16x8 af = *(const bf16x8*)(ab + row * 128 + ((64 * cc + 16 * hi) ^ ((row & 7) << 4)));
        #pragma unroll
        for (int e = 0; e < 3; ++e)
          acc[e][m] = __builtin_amdgcn_mfma_f32_16x16x32_bf16(af, wf[e], acc[e][m], 0, 0, 0);
      }
    }
    __syncthreads();
  }

  // ---- fused gate epilogue ----
  const int d = 16 * tq + lo;
  const float bb1 = b1[d], bb2 = b2[d], bb3 = b3[d];
  #pragma unroll
  for (int m = 0; m < 8; ++m){
    #pragma unroll
    for (int r = 0; r < 4; ++r){
      const int row = m0 + 16 * m + 4 * hi + r;
      float y1 = acc[0][m][r] + bb1;
      float y2 = acc[1][m][r] + bb2;
      float y3 = acc[2][m][r] + bb3;
      float pv = bf2f(Pbf[(size_t)row * ND + d]);
      float e2 = __expf(2.f * y1);
      float z  = (e2 - 1.f) / (e2 + 1.f);          // tanh
      float rr = 1.f / (1.f + __expf(-y2));        // sigmoid
      float ff = 1.f / (1.f + __expf(-y3));        // sigmoid
      out[(size_t)row * ND + d] = rr * pv + ff * z;
    }
  }
}

extern "C" void kernel_launch(void* const* d_in, const int* in_sizes, int n_in,
                              void* d_out, int out_size, void* d_ws, size_t ws_size,
                              hipStream_t stream){
  const float* P  = (const float*)d_in[0];
  const float* wi = (const float*)d_in[1];
  const float* w1 = (const float*)d_in[2];
  const float* w2 = (const float*)d_in[3];
  const float* w3 = (const float*)d_in[4];
  const float* b1 = (const float*)d_in[5];
  const float* b2 = (const float*)d_in[6];
  const float* b3 = (const float*)d_in[7];
  float* out = (float*)d_out;

  char* ws = (char*)d_ws;
  u16*   Pbf   = (u16*)  (ws);                        // 16 MB
  u16*   PbfT  = (u16*)  (ws + (16u << 20));          // 16 MB
  u16*   attnb = (u16*)  (ws + (32u << 20));          // 16 MB
  u16*   Wp    = (u16*)  (ws + (48u << 20));          // 768 KB packed fragments
  float* sbv   = (float*)(ws + (49u << 20));          // 128 KB

  prep_rows<<<8192, 256, 0, stream>>>(P, wi, Pbf, sbv);
  prep_w<<<48, 256, 0, stream>>>(w1, w2, w3, Wp);
  transpose_p<<<dim3(16, 4, 32), 256, 0, stream>>>(Pbf, PbfT);
  attn_kernel<<<1024, 128, 0, stream>>>(P, wi, Pbf, PbfT, sbv, attnb);
  mlp_kernel<<<1024, 256, 0, stream>>>(Pbf, attnb, Wp, b1, b2, b3, out);
}

// Round 12
// 126.454 us; speedup vs baseline: 1.0523x; 1.0523x over previous
//
#include <hip/hip_runtime.h>
#include <hip/hip_bf16.h>

typedef unsigned short u16;
typedef unsigned int   u32;

using bf16x8 = __attribute__((ext_vector_type(8))) short;  // 8 bf16 in 4 VGPRs
using bf16x4 = __attribute__((ext_vector_type(4))) short;  // 4 bf16 in 2 VGPRs
using f32x4  = __attribute__((ext_vector_type(4))) float;  // MFMA accumulator

#define NB 32
#define NP 1024
#define ND 256

__device__ __forceinline__ u16 f2bf(float x){
  u32 u = __float_as_uint(x);
  u += 0x7FFFu + ((u >> 16) & 1u);   // round-to-nearest-even
  return (u16)(u >> 16);
}

__device__ __forceinline__ float bf2f(u16 x){
  return __uint_as_float((u32)x << 16);
}

__device__ __forceinline__ void glds16(const void* g, void* l){
  __builtin_amdgcn_global_load_lds((const __attribute__((address_space(1))) void*)g,
                                   (__attribute__((address_space(3))) void*)l, 16, 0, 0);
}

// PV MFMA: 16x16x16 bf16. Prefer the _1k builtin; fall back to zero-padded
// 16x16x32 (upper k-half zeros on both operands -> mathematically identical).
#if __has_builtin(__builtin_amdgcn_mfma_f32_16x16x16bf16_1k)
__device__ __forceinline__ f32x4 mfma16(bf16x4 a, bf16x4 b, f32x4 c){
  return __builtin_amdgcn_mfma_f32_16x16x16bf16_1k(a, b, c, 0, 0, 0);
}
#else
__device__ __forceinline__ f32x4 mfma16(bf16x4 a, bf16x4 b, f32x4 c){
  bf16x8 a8 = {a[0], a[1], a[2], a[3], 0, 0, 0, 0};
  bf16x8 b8 = {b[0], b[1], b[2], b[3], 0, 0, 0, 0};
  return __builtin_amdgcn_mfma_f32_16x16x32_bf16(a8, b8, c, 0, 0, 0);
}
#endif

// ---------------- prep 1: Pbf = bf16(P), sbv[row] = P[row,:] . wb ----------------
__global__ void prep_rows(const float* __restrict__ P, const float* __restrict__ wi,
                          u16* __restrict__ Pbf, float* __restrict__ sbv){
  const int row  = blockIdx.x * 4 + (threadIdx.x >> 6);   // one wave per row
  const int lane = threadIdx.x & 63;
  const float4 p  = *(const float4*)(P  + (size_t)row * ND + lane * 4);
  const float4 wb = *(const float4*)(wi + ND + lane * 4);  // wb = wi[256:512]
  ushort4 pb;
  pb.x = f2bf(p.x); pb.y = f2bf(p.y); pb.z = f2bf(p.z); pb.w = f2bf(p.w);
  *(ushort4*)(Pbf + (size_t)row * ND + lane * 4) = pb;
  float s = p.x*wb.x + p.y*wb.y + p.z*wb.z + p.w*wb.w;
  #pragma unroll
  for (int m = 1; m < 64; m <<= 1) s += __shfl_xor(s, m, 64);
  if (lane == 0) sbv[row] = s;
}

// ------- prep 2: pack W fragment-major: Wp[((t*16+c)*64+lane)*8 + e] -------------
__global__ void prep_w(const float* __restrict__ w1, const float* __restrict__ w2,
                       const float* __restrict__ w3, u16* __restrict__ Wp){
  const int t = blockIdx.x;                       // 0..47
  const float* w = (t < 16) ? w1 : ((t < 32) ? w2 : w3);
  const int tid = threadIdx.x;
  #pragma unroll
  for (int j = 0; j < 4; ++j){
    int item = tid + 256 * j;                     // c*64 + lane
    int c = item >> 6, lane = item & 63;
    int ncol = ((t & 15) << 4) + (lane & 15);
    int k0 = 32 * c + 8 * (lane >> 4);
    u16 tmp[8];
    #pragma unroll
    for (int e = 0; e < 8; ++e) tmp[e] = f2bf(w[(size_t)(k0 + e) * 256 + ncol]);
    *(uint4*)(Wp + ((size_t)(t * 16 + c) * 64 + lane) * 8) = *(uint4*)tmp;
  }
}

// ---------------- prep 3: PbfT[b][d][j] = Pbf[b][j][d] (64x64 LDS tiles) ---------
__global__ void transpose_p(const u16* __restrict__ Pbf, u16* __restrict__ PbfT){
  const int b = blockIdx.z, jt = blockIdx.x, dt = blockIdx.y;
  __shared__ u16 T[64][72];
  const int tid = threadIdx.x;
  #pragma unroll
  for (int it = 0; it < 2; ++it){
    int cc = tid + 256 * it;               // 0..511: 64 j-rows x 8 chunks
    int j = cc >> 3, c8 = cc & 7;
    uint4 v = *(const uint4*)(Pbf + ((size_t)b * NP + jt * 64 + j) * ND + dt * 64 + c8 * 8);
    *(uint4*)&T[j][c8 * 8] = v;
  }
  __syncthreads();
  #pragma unroll
  for (int it = 0; it < 2; ++it){
    int cc = tid + 256 * it;               // 64 d-rows x 8 chunks
    int d = cc >> 3, c8 = cc & 7;
    u16 tmp[8];
    #pragma unroll
    for (int k = 0; k < 8; ++k) tmp[k] = T[c8 * 8 + k][d];
    *(uint4*)(PbfT + ((size_t)b * ND + dt * 64 + d) * NP + jt * 64 + c8 * 8) = *(uint4*)tmp;
  }
}

// ---------------- attention: QBLK=64, KBLK=64, SWAPPED QK^T, no P-LDS ------------
// Memory structure identical to r10 (best measured): K/V layouts, glds staging,
// split barriers, 2 blocks/CU. Compute restructured:
//   QK^T computed SWAPPED: mfma(K, Q) -> S^T tile: col = lane&15 = q-row,
//   row = 16nt+4hi+r = key j. Each lane holds P[q=lo][j=16nt+4hi+r], which IS
//   the A-fragment of mfma_f32_16x16x16_bf16 (row=lo, k=4hi+e) for PV k-tile nt:
//   P goes register->MFMA directly. The Sp LDS repack (16 conflicted u16 writes +
//   2 b128 reads per tile per wave; the 4.45M-conflict source since r2) is GONE.
//   Softmax becomes lane-local (mx, ls scalars; cross-lane only on rare slow path
//   = 2 shfl_xor). V read becomes b64 at V^T[d][16nt+4hi..+3]: banks
//   4*((2nt+(hi>>1))^(lo&7)) + 2(hi&1) -> bijective per 8-lane group, clean.
__launch_bounds__(256, 2)
__global__ void attn_kernel(const float* __restrict__ P, const float* __restrict__ wi,
                            const u16* __restrict__ Pbf, const u16* __restrict__ PbfT,
                            const float* __restrict__ sbv, u16* __restrict__ attnb){
  const int p    = blockIdx.x;
  const int bid  = ((p & 7) << 6) | (p >> 3);     // 64 consecutive bids per XCD
  const int b    = bid >> 4;
  const int q0   = (bid & 15) << 6;
  const int tid  = threadIdx.x;
  const int wave = tid >> 6, lane = tid & 63, lo = lane & 15, hi = lane >> 4;

  __shared__ __align__(16) u16 KtA[64 * 256];     // 32 KB
  __shared__ __align__(16) u16 VtA[256 * 64];     // 32 KB
  char* KtB = (char*)KtA;
  char* VtB = (char*)VtA;

  // ---- Q fragments (B-operand now; same layout: col=lo=q, k=8hi+e) ----
  bf16x8 qf[8];
  {
    const int qrow = q0 + wave * 16 + lo;
    const float* prow = P  + ((size_t)b * NP + qrow) * ND;
    const float* wcp  = wi + 512;
    #pragma unroll
    for (int c = 0; c < 8; ++c){
      const int d0 = 32 * c + 8 * hi;
      float4 a  = *(const float4*)(prow + d0);
      float4 a2 = *(const float4*)(prow + d0 + 4);
      float4 wa  = *(const float4*)(wcp + d0);
      float4 wa2 = *(const float4*)(wcp + d0 + 4);
      bf16x8 q;
      q[0]=(short)f2bf(a.x*wa.x);  q[1]=(short)f2bf(a.y*wa.y);
      q[2]=(short)f2bf(a.z*wa.z);  q[3]=(short)f2bf(a.w*wa.w);
      q[4]=(short)f2bf(a2.x*wa2.x); q[5]=(short)f2bf(a2.y*wa2.y);
      q[6]=(short)f2bf(a2.z*wa2.z); q[7]=(short)f2bf(a2.w*wa2.w);
      qf[c] = q;
    }
  }

  f32x4 of[16];
  #pragma unroll
  for (int t = 0; t < 16; ++t) of[t] = (f32x4){0.f,0.f,0.f,0.f};
  float mx = -1e30f;     // running max of row q = lo (lane-local)
  float ls = 0.f;        // lane-partial softmax sum for row q = lo

  const u16* kslab = Pbf  + (size_t)b * NP * ND;   // row-major [j][d]
  const u16* vslab = PbfT + (size_t)b * ND * NP;   // d-major  [d][j]

  auto stageK = [&](int kt){
    const int kbase = kt * 64;
    #pragma unroll
    for (int it = 0; it < 8; ++it){
      int off = it * 4096 + tid * 16;             // linear LDS dest byte
      int j   = off >> 9;
      int ck  = ((off >> 4) & 31) ^ (j & 7);
      glds16((const char*)(kslab + (size_t)(kbase + j) * ND + ck * 8), KtB + off);
    }
  };
  auto stageV = [&](int kt){
    const int kbase = kt * 64;
    #pragma unroll
    for (int it = 0; it < 8; ++it){
      int off = it * 4096 + tid * 16;
      int d   = off >> 7;
      int kc  = ((off >> 4) & 7) ^ (d & 7);
      glds16((const char*)(vslab + (size_t)d * NP + kbase + kc * 8), VtB + off);
    }
  };

  stageK(0);
  stageV(0);
  __syncthreads();                                 // drain: K0,V0 valid

  for (int kt = 0; kt < 16; ++kt){
    const int kbase = kt * 64;

    // ---- S^T = K Q (swapped): lane holds S[j=16nt+4hi+r][q=lo] ----
    f32x4 s[4];
    #pragma unroll
    for (int nt = 0; nt < 4; ++nt){
      f32x4 acc = (f32x4){0.f,0.f,0.f,0.f};
      #pragma unroll
      for (int c = 0; c < 8; ++c){
        int j  = nt * 16 + lo;
        int ad = j * 512 + (((4 * c + hi) ^ (j & 7)) << 4);
        bf16x8 kf = *(const bf16x8*)(KtB + ad);
        acc = __builtin_amdgcn_mfma_f32_16x16x32_bf16(kf, qf[c], acc, 0, 0, 0);
      }
      s[nt] = acc;
    }
    __syncthreads();                  // barrier1: all waves done reading Kt
    if (kt < 15) stageK(kt + 1);      // in flight across softmax+PV; drained at barrier2

    // ---- add sb[j] (float4: j = kbase+16nt+4hi+{0..3}) ----
    #pragma unroll
    for (int nt = 0; nt < 4; ++nt){
      float4 sq = *(const float4*)(sbv + (size_t)b * NP + kbase + 16 * nt + 4 * hi);
      s[nt][0] += sq.x; s[nt][1] += sq.y; s[nt][2] += sq.z; s[nt][3] += sq.w;
    }

    // ---- deferred online softmax (lane-local row q = lo) ----
    float vmax = s[0][0];
    #pragma unroll
    for (int nt = 0; nt < 4; ++nt)
      #pragma unroll
      for (int r = 0; r < 4; ++r) vmax = fmaxf(vmax, s[nt][r]);
    if (!__all(vmax - mx <= 8.f)){
      // slow path: full row max across the 4 hi-lanes sharing q=lo, rescale O
      float v = fmaxf(vmax, __shfl_xor(vmax, 16, 64));
      v = fmaxf(v, __shfl_xor(v, 32, 64));
      float mnew = fmaxf(mx, v);
      float sc = __expf(mx - mnew);
      mx = mnew; ls *= sc;
      float scr[4];
      #pragma unroll
      for (int r = 0; r < 4; ++r) scr[r] = __shfl(sc, 4 * hi + r, 64);
      #pragma unroll
      for (int t = 0; t < 16; ++t)
        #pragma unroll
        for (int r = 0; r < 4; ++r) of[t][r] *= scr[r];
    }
    // common path: exp + lane-partial sum + pack A-frags (NO LDS, NO shuffles)
    bf16x4 pa[4];
    #pragma unroll
    for (int nt = 0; nt < 4; ++nt){
      float e0 = __expf(s[nt][0] - mx);
      float e1 = __expf(s[nt][1] - mx);
      float e2 = __expf(s[nt][2] - mx);
      float e3 = __expf(s[nt][3] - mx);
      ls += (e0 + e1) + (e2 + e3);
      bf16x4 w;
      w[0] = (short)f2bf(e0); w[1] = (short)f2bf(e1);
      w[2] = (short)f2bf(e2); w[3] = (short)f2bf(e3);
      pa[nt] = w;
    }

    // ---- O += P V : A = pa[nt] (regs), B = V^T[d][16nt+4hi..+3] b64 reads ----
    #pragma unroll
    for (int nt = 0; nt < 4; ++nt){
      const int cswz = (2 * nt + (hi >> 1));
      const int sub  = 8 * (hi & 1);
      #pragma unroll
      for (int t = 0; t < 16; ++t){
        int d  = 16 * t + lo;
        int ad = d * 128 + ((cswz ^ (d & 7)) << 4) + sub;
        bf16x4 vb = *(const bf16x4*)(VtB + ad);
        of[t] = mfma16(pa[nt], vb, of[t]);
      }
    }

    __syncthreads();                  // barrier2: Vt reads done; drains K(t+1) glds
    if (kt < 15) stageV(kt + 1);      // in flight across next QK^T; drained at barrier1
  }

  // ---- epilogue: row-sum (2 shfls), O /= l, store bf16 ----
  float ltot = ls;
  ltot += __shfl_xor(ltot, 16, 64);
  ltot += __shfl_xor(ltot, 32, 64);
  float lr[4];
  #pragma unroll
  for (int r = 0; r < 4; ++r) lr[r] = __shfl(ltot, 4 * hi + r, 64);
  const int qrow = q0 + wave * 16;
  #pragma unroll
  for (int t = 0; t < 16; ++t){
    #pragma unroll
    for (int r = 0; r < 4; ++r){
      float o = of[t][r] / lr[r];
      attnb[((size_t)b * NP + qrow + 4 * hi + r) * ND + 16 * t + lo] = f2bf(o);
    }
  }
}

// ---------------- MLP: proper GEMM, M-tile 128, fused gate epilogue --------------
// NOTE: acc[3][8] = 96 VGPRs of accumulator. __launch_bounds__ min-waves MUST stay
// at 2 (VGPR budget 256): round-5's (256,4) capped the allocator at 64 VGPR and
// spilled all accumulators to scratch (WRITE_SIZE 33 -> 325 MB, 18 -> 136 us).
__launch_bounds__(256, 2)
__global__ void mlp_kernel(const u16* __restrict__ Pbf, const u16* __restrict__ attnb,
                           const u16* __restrict__ Wp,
                           const float* __restrict__ b1, const float* __restrict__ b2,
                           const float* __restrict__ b3, float* __restrict__ out){
  const int p    = blockIdx.x;
  const int swz  = ((p & 7) << 7) | (p >> 3);     // XCD-chunked
  const int mt   = swz >> 2, cg = swz & 3;
  const int tid  = threadIdx.x;
  const int wave = tid >> 6, lane = tid & 63, lo = lane & 15, hi = lane >> 4;
  const int tq   = 4 * cg + wave;
  const int m0   = mt * 128;

  __shared__ __align__(16) u16 Ab[2][128 * 64];   // 2 x 16 KB, swizzled

  f32x4 acc[3][8];
  #pragma unroll
  for (int e = 0; e < 3; ++e)
    #pragma unroll
    for (int m = 0; m < 8; ++m) acc[e][m] = (f32x4){0.f,0.f,0.f,0.f};

  auto stage = [&](int s, int buf){
    const u16* xs = (s < 4) ? (Pbf   + (size_t)m0 * ND + s * 64)
                            : (attnb + (size_t)m0 * ND + (s - 4) * 64);
    char* dst = (char*)Ab[buf];
    #pragma unroll
    for (int it = 0; it < 4; ++it){
      int off = it * 4096 + wave * 1024 + lane * 16;   // physical LDS byte
      int row = off >> 7;                               // 128B per row
      int cl  = (off & 127) ^ ((row & 7) << 4);         // logical byte in row
      glds16((const char*)(xs + (size_t)row * ND) + cl, dst + it * 4096 + wave * 1024);
    }
  };

  stage(0, 0);
  __syncthreads();

  for (int s = 0; s < 8; ++s){
    if (s < 7) stage(s + 1, (s + 1) & 1);
    const char* ab = (const char*)Ab[s & 1];
    #pragma unroll
    for (int cc = 0; cc < 2; ++cc){
      const int c = 2 * s + cc;
      bf16x8 wf[3];
      #pragma unroll
      for (int e = 0; e < 3; ++e)
        wf[e] = *(const bf16x8*)(Wp + ((size_t)((tq + 16 * e) * 16 + c) * 64 + lane) * 8);
      #pragma unroll
      for (int m = 0; m < 8; ++m){
        int row = 16 * m + lo;
        bf16x8 af = *(const bf16x8*)(ab + row * 128 + ((64 * cc + 16 * hi) ^ ((row & 7) << 4)));
        #pragma unroll
        for (int e = 0; e < 3; ++e)
          acc[e][m] = __builtin_amdgcn_mfma_f32_16x16x32_bf16(af, wf[e], acc[e][m], 0, 0, 0);
      }
    }
    __syncthreads();
  }

  // ---- fused gate epilogue ----
  const int d = 16 * tq + lo;
  const float bb1 = b1[d], bb2 = b2[d], bb3 = b3[d];
  #pragma unroll
  for (int m = 0; m < 8; ++m){
    #pragma unroll
    for (int r = 0; r < 4; ++r){
      const int row = m0 + 16 * m + 4 * hi + r;
      float y1 = acc[0][m][r] + bb1;
      float y2 = acc[1][m][r] + bb2;
      float y3 = acc[2][m][r] + bb3;
      float pv = bf2f(Pbf[(size_t)row * ND + d]);
      float e2 = __expf(2.f * y1);
      float z  = (e2 - 1.f) / (e2 + 1.f);          // tanh
      float rr = 1.f / (1.f + __expf(-y2));        // sigmoid
      float ff = 1.f / (1.f + __expf(-y3));        // sigmoid
      out[(size_t)row * ND + d] = rr * pv + ff * z;
    }
  }
}

extern "C" void kernel_launch(void* const* d_in, const int* in_sizes, int n_in,
                              void* d_out, int out_size, void* d_ws, size_t ws_size,
                              hipStream_t stream){
  const float* P  = (const float*)d_in[0];
  const float* wi = (const float*)d_in[1];
  const float* w1 = (const float*)d_in[2];
  const float* w2 = (const float*)d_in[3];
  const float* w3 = (const float*)d_in[4];
  const float* b1 = (const float*)d_in[5];
  const float* b2 = (const float*)d_in[6];
  const float* b3 = (const float*)d_in[7];
  float* out = (float*)d_out;

  char* ws = (char*)d_ws;
  u16*   Pbf   = (u16*)  (ws);                        // 16 MB
  u16*   PbfT  = (u16*)  (ws + (16u << 20));          // 16 MB
  u16*   attnb = (u16*)  (ws + (32u << 20));          // 16 MB
  u16*   Wp    = (u16*)  (ws + (48u << 20));          // 768 KB packed fragments
  float* sbv   = (float*)(ws + (49u << 20));          // 128 KB

  prep_rows<<<8192, 256, 0, stream>>>(P, wi, Pbf, sbv);
  prep_w<<<48, 256, 0, stream>>>(w1, w2, w3, Wp);
  transpose_p<<<dim3(16, 4, 32), 256, 0, stream>>>(Pbf, PbfT);
  attn_kernel<<<512, 256, 0, stream>>>(P, wi, Pbf, PbfT, sbv, attnb);
  mlp_kernel<<<1024, 256, 0, stream>>>(Pbf, attnb, Wp, b1, b2, b3, out);
}